// Round 3
// baseline (762.180 us; speedup 1.0000x reference)
//
#include <hip/hip_runtime.h>
#include <hip/hip_bf16.h>

// Experts MLP: B=4,E=8,S=1024,D=1024,H=2048. Inputs/outputs FLOAT32 (per the
// reference's setup_inputs dtypes); internally converted to bf16 for MFMA.
// Flat: x is (E*4096,1024) expert-major; expert e owns rows [e*4096,(e+1)*4096).
//   H_e = gelu_exact(X_e @ W1[e] + b1[e]);  Out_e = H_e @ W2[e] + b2[e]
//
// Round-2 post-mortem: NaN under all-bf16 interpretation has no mechanism
// (poison reads are finite, kernels verified vs m92/m97 patterns). NaN IS
// mechanically explained by reading fp32 data as bf16 (random low ushorts ->
// ~0.4% NaN patterns). This round: fp32 in/out, bf16 compute.

typedef __attribute__((ext_vector_type(8))) short bf16x8;
typedef __attribute__((ext_vector_type(4))) float f32x4;

__device__ __forceinline__ ushort f2bf(float f) {
    __hip_bfloat16 h = __float2bfloat16(f);
    return *(ushort*)&h;
}

__device__ __forceinline__ void async16(const ushort* g, ushort* l) {
    __builtin_amdgcn_global_load_lds(
        (const __attribute__((address_space(1))) unsigned int*)g,
        (__attribute__((address_space(3))) unsigned int*)l, 16, 0, 0);
}

// ---------------------------------------------------------------------------
// fp32 -> bf16 elementwise cast, float4 -> 4x bf16 per thread-iter.
// ---------------------------------------------------------------------------
__global__ __launch_bounds__(256) void cvt_f32_bf16(
    const float4* __restrict__ src, uint2* __restrict__ dst, long n4)
{
    long i = (long)blockIdx.x * 256 + threadIdx.x;
    const long stride = (long)gridDim.x * 256;
    for (; i < n4; i += stride) {
        float4 v = src[i];
        uint2 o;
        o.x = (unsigned)f2bf(v.x) | ((unsigned)f2bf(v.y) << 16);
        o.y = (unsigned)f2bf(v.z) | ((unsigned)f2bf(v.w) << 16);
        dst[i] = o;
    }
}

// ---------------------------------------------------------------------------
// Transpose+convert: fp32 (R,C) -> bf16 (C,R), per expert (grid.z).
// grid(C/64, R/64, E), 256 threads, 64x64 tile via LDS (65-pad).
// ---------------------------------------------------------------------------
__global__ __launch_bounds__(256) void transpose_cvt(
    const float* __restrict__ src, ushort* __restrict__ dst, int R, int C)
{
    __shared__ float tile[64][65];
    const int e = blockIdx.z;
    const float* s = src + (size_t)e * R * C;
    ushort* d = dst + (size_t)e * R * C;
    const int r0 = blockIdx.y * 64, c0 = blockIdx.x * 64;
    const int tid = threadIdx.x;

    const int tr = tid >> 4;          // 0..15
    const int tc = (tid & 15) * 4;    // 0..60
#pragma unroll
    for (int j = 0; j < 4; ++j) {
        const int row = tr + j * 16;
        float4 v = *(const float4*)&s[(size_t)(r0 + row) * C + c0 + tc];
        tile[row][tc] = v.x; tile[row][tc + 1] = v.y;
        tile[row][tc + 2] = v.z; tile[row][tc + 3] = v.w;
    }
    __syncthreads();

    const int cc = tid >> 2;          // dst row (src col) 0..63
    const int rq = (tid & 3) * 16;    // dst col base
    ushort o[16];
#pragma unroll
    for (int j = 0; j < 16; ++j) o[j] = f2bf(tile[rq + j][cc]);
    *(uint4*)&d[(size_t)(c0 + cc) * R + r0 + rq]     = *(uint4*)&o[0];
    *(uint4*)&d[(size_t)(c0 + cc) * R + r0 + rq + 8] = *(uint4*)&o[8];
}

// ---------------------------------------------------------------------------
// GEMM: C(M,N) = A(M,K) @ BT(N,K)^T + bias(fp32), optional exact GELU.
// A,BT bf16; fp32 accum; OUT fp32 (OUTF32=1) or bf16. m97 structure:
// 128x128 tile, 4 waves 2x2, 4x4 of 16x16x32 MFMA, BK=32, width-16
// global_load_lds staging. grid(N/128, M/128, nE).
// ---------------------------------------------------------------------------
template <int GELU, int OUTF32>
__global__ __launch_bounds__(256) void gemm_bt(
    const ushort* __restrict__ A,
    const ushort* __restrict__ BT,
    const float* __restrict__ bias,
    void* __restrict__ Cv,
    int M, int N, int K)
{
    const int e = blockIdx.z;
    const ushort* Ab = A + (size_t)e * M * K;
    const ushort* Bb = BT + (size_t)e * N * K;
    const float* biasb = bias + (size_t)e * N;

    const int row0 = blockIdx.y * 128;
    const int col0 = blockIdx.x * 128;
    const int tid = threadIdx.x;
    const int lane = tid & 63;
    const int wave = tid >> 6;
    const int wy = wave >> 1, wx = wave & 1;
    const int lr = lane & 15;   // row (A) / col (B) within 16
    const int lk = lane >> 4;   // k-quad 0..3

    __shared__ ushort sA[128 * 32];
    __shared__ ushort sB[128 * 32];

    f32x4 acc[4][4] = {};

    const int nkt = K >> 5;
    for (int kt = 0; kt < nkt; ++kt) {
        __syncthreads();  // prior iteration's ds_reads complete
#pragma unroll
        for (int i = 0; i < 2; ++i) {
            const int c = i * 256 + tid;       // 16B-chunk id 0..511
            const int r = c >> 2;              // tile row 0..127
            const int kc = c & 3;              // 8-elem chunk in BK=32
            async16(Ab + (size_t)(row0 + r) * K + kt * 32 + kc * 8, &sA[c * 8]);
            async16(Bb + (size_t)(col0 + r) * K + kt * 32 + kc * 8, &sB[c * 8]);
        }
        __syncthreads();  // vmcnt drained: staging visible

        bf16x8 af[4], bfr[4];
#pragma unroll
        for (int mi = 0; mi < 4; ++mi)
            af[mi] = *(const bf16x8*)&sA[(wy * 64 + mi * 16 + lr) * 32 + lk * 8];
#pragma unroll
        for (int ni = 0; ni < 4; ++ni)
            bfr[ni] = *(const bf16x8*)&sB[(wx * 64 + ni * 16 + lr) * 32 + lk * 8];
#pragma unroll
        for (int mi = 0; mi < 4; ++mi)
#pragma unroll
            for (int ni = 0; ni < 4; ++ni)
                acc[mi][ni] = __builtin_amdgcn_mfma_f32_16x16x32_bf16(
                    af[mi], bfr[ni], acc[mi][ni], 0, 0, 0);
    }

    // Epilogue. C/D layout (m89/m91-verified): col=lane&15, row=(lane>>4)*4+reg.
#pragma unroll
    for (int mi = 0; mi < 4; ++mi) {
#pragma unroll
        for (int ni = 0; ni < 4; ++ni) {
            const int col = col0 + wx * 64 + ni * 16 + lr;
            const float bv = biasb[col];
#pragma unroll
            for (int r = 0; r < 4; ++r) {
                const int row = row0 + wy * 64 + mi * 16 + lk * 4 + r;
                float v = acc[mi][ni][r] + bv;
                if (GELU)
                    v = 0.5f * v * (1.0f + erff(v * 0.70710678118654752f));
                const size_t idx = (size_t)e * M * N + (size_t)row * N + col;
                if (OUTF32) ((float*)Cv)[idx] = v;
                else        ((ushort*)Cv)[idx] = f2bf(v);
            }
        }
    }
}

extern "C" void kernel_launch(void* const* d_in, const int* in_sizes, int n_in,
                              void* d_out, int out_size, void* d_ws, size_t ws_size,
                              hipStream_t stream)
{
    const float* x  = (const float*)d_in[0];  // (8,4096,1024) flat expert-major
    const float* w1 = (const float*)d_in[1];  // (8,1024,2048)
    const float* b1 = (const float*)d_in[2];  // (8,2048)
    const float* w2 = (const float*)d_in[3];  // (8,2048,1024)
    const float* b2 = (const float*)d_in[4];  // (8,1024)
    float* out = (float*)d_out;               // (8,4096,1024) fp32

    const size_t W1T = 8ull * 2048 * 1024 * 2;   // 33.5 MB bf16, all experts
    const size_t W2T = 8ull * 1024 * 2048 * 2;   // 33.5 MB
    const size_t W1TE = 2048ull * 1024 * 2;      // 4.2 MB single expert
    const size_t W2TE = 1024ull * 2048 * 2;      // 4.2 MB
    const size_t XB_E = 4096ull * 1024 * 2;      // 8.4 MB bf16 x, one expert
    const size_t H_E  = 4096ull * 2048 * 2;      // 16.8 MB bf16 H, one expert

    char* ws = (char*)d_ws;

    // Level A: all-expert weight transposes + chunk of experts at once.
    int chunk = 0;
    for (int c = 8; c >= 1; c >>= 1)
        if (ws_size >= W1T + W2T + (size_t)c * (XB_E + H_E)) { chunk = c; break; }

    if (chunk >= 1) {
        ushort* w1t = (ushort*)ws;
        ushort* w2t = (ushort*)(ws + W1T);
        ushort* xb  = (ushort*)(ws + W1T + W2T);
        ushort* Hb  = (ushort*)(ws + W1T + W2T + (size_t)chunk * XB_E);

        transpose_cvt<<<dim3(2048 / 64, 1024 / 64, 8), 256, 0, stream>>>(
            w1, w1t, 1024, 2048);
        transpose_cvt<<<dim3(1024 / 64, 2048 / 64, 8), 256, 0, stream>>>(
            w2, w2t, 2048, 1024);

        for (int e0 = 0; e0 < 8; e0 += chunk) {
            const long n4 = (long)chunk * 4096 * 1024 / 4;
            cvt_f32_bf16<<<dim3(8192), 256, 0, stream>>>(
                (const float4*)(x + (size_t)e0 * 4096 * 1024), (uint2*)xb, n4);
            gemm_bt<1, 0><<<dim3(2048 / 128, 4096 / 128, chunk), 256, 0, stream>>>(
                xb, w1t + (size_t)e0 * 2048 * 1024, b1 + (size_t)e0 * 2048,
                Hb, 4096, 2048, 1024);
            gemm_bt<0, 1><<<dim3(1024 / 128, 4096 / 128, chunk), 256, 0, stream>>>(
                Hb, w2t + (size_t)e0 * 1024 * 2048, b2 + (size_t)e0 * 1024,
                out + (size_t)e0 * 4096 * 1024, 4096, 1024, 2048);
        }
        return;
    }

    // Level B/C: per-expert weights + token strips sized to ws.
    int strip = 0;
    if      (ws_size >= W1TE + W2TE + XB_E + H_E)             strip = 4096;
    else if (ws_size >= W1TE + W2TE + (XB_E + H_E) / 4)       strip = 1024;
    else                                                      strip = 128;

    ushort* w1t = (ushort*)ws;
    ushort* w2t = (ushort*)(ws + W1TE);
    ushort* xb  = (ushort*)(ws + W1TE + W2TE);
    ushort* Hb  = (ushort*)(ws + W1TE + W2TE + (size_t)strip * 1024 * 2);

    for (int e = 0; e < 8; ++e) {
        transpose_cvt<<<dim3(2048 / 64, 1024 / 64, 1), 256, 0, stream>>>(
            w1 + (size_t)e * 1024 * 2048, w1t, 1024, 2048);
        transpose_cvt<<<dim3(1024 / 64, 2048 / 64, 1), 256, 0, stream>>>(
            w2 + (size_t)e * 2048 * 1024, w2t, 2048, 1024);
        for (int s0 = 0; s0 < 4096; s0 += strip) {
            const long n4 = (long)strip * 1024 / 4;
            cvt_f32_bf16<<<dim3(2048), 256, 0, stream>>>(
                (const float4*)(x + ((size_t)e * 4096 + s0) * 1024), (uint2*)xb, n4);
            gemm_bt<1, 0><<<dim3(2048 / 128, strip / 128, 1), 256, 0, stream>>>(
                xb, w1t, b1 + (size_t)e * 2048, Hb, strip, 2048, 1024);
            gemm_bt<0, 1><<<dim3(1024 / 128, strip / 128, 1), 256, 0, stream>>>(
                Hb, w2t, b2 + (size_t)e * 1024,
                out + ((size_t)e * 4096 + s0) * 1024, strip, 1024, 2048);
        }
    }
}